// Round 10
// baseline (203.758 us; speedup 1.0000x reference)
//
#include <hip/hip_runtime.h>
#include <stdint.h>

typedef __attribute__((ext_vector_type(8))) __bf16 bf16x8;
typedef __attribute__((ext_vector_type(4))) __bf16 bf16x4;
typedef __attribute__((ext_vector_type(4))) float f32x4;

#define MFMA16(a, b, c) __builtin_amdgcn_mfma_f32_16x16x32_bf16(a, b, c, 0, 0, 0)

// async 16B global->LDS: lds dest must be wave-uniform base; lane writes at base+lane*16
__device__ __forceinline__ void async_ld16(const __bf16* g, __bf16* lds_base) {
    __builtin_amdgcn_global_load_lds(
        (const __attribute__((address_space(1))) void*)g,
        (__attribute__((address_space(3))) void*)lds_base, 16, 0, 0);
}

// ---------------------------------------------------------------- fused prep
// bid < 4096:            cast hs fp32 -> bf16 (4M elems)
// 4096 <= bid < 7168:    transpose-cast w1 [1024,3072] -> w1t [3072,1024]
// bid >= 7168:           transpose-cast w2 [1024,1024] -> w2t [1024,1024]
__global__ __launch_bounds__(256) void k_prep(
    const float* __restrict__ hs, const float* __restrict__ w1,
    const float* __restrict__ w2, __bf16* __restrict__ hsb,
    __bf16* __restrict__ w1t, __bf16* __restrict__ w2t) {
    __shared__ __bf16 tile[32][33];
    int bid = blockIdx.x, tid = threadIdx.x;
    if (bid < 4096) {
        int i = (bid * 256 + tid) * 4;
        float4 v = *(const float4*)(hs + i);
        bf16x4 o;
        o.x = (__bf16)v.x; o.y = (__bf16)v.y; o.z = (__bf16)v.z; o.w = (__bf16)v.w;
        *(bf16x4*)(hsb + i) = o;
        return;
    }
    const float* in; __bf16* out; int C, tb;
    if (bid < 7168) { in = w1; out = w1t; C = 3072; tb = bid - 4096; }
    else            { in = w2; out = w2t; C = 1024; tb = bid - 7168; }
    const int R = 1024;
    int ntc = C >> 5;
    int c0 = (tb % ntc) * 32, r0 = (tb / ntc) * 32;
    int tx = tid & 31, ty = tid >> 5;  // 32 x 8
#pragma unroll
    for (int i = 0; i < 4; i++)
        tile[ty + i * 8][tx] = (__bf16)in[(size_t)(r0 + ty + i * 8) * C + c0 + tx];
    __syncthreads();
#pragma unroll
    for (int i = 0; i < 4; i++)
        out[(size_t)(c0 + ty + i * 8) * R + r0 + tx] = tile[tx][ty + i * 8];
}

// ---------------------------------------------------------------- QKV GEMM (m97-style)
__global__ __launch_bounds__(256, 2) void k_gemm_qkv(
    const __bf16* __restrict__ A, const __bf16* __restrict__ Bt,
    const float* __restrict__ bias,
    __bf16* __restrict__ Qo, __bf16* __restrict__ Ko, __bf16* __restrict__ Vo) {
    __shared__ __bf16 As[128 * 32];
    __shared__ __bf16 Bs[128 * 32];
    const int Kd = 1024;
    int n0 = blockIdx.x * 128, m0 = blockIdx.y * 128;
    int tid = threadIdx.x;
    int wv = tid >> 6, lane = tid & 63;
    int wm = (wv >> 1) * 64, wn = (wv & 1) * 64;
    int quad = lane >> 4, l16 = lane & 15;
    int lrow = lane >> 2, lcol = (lane & 3) * 8;
    f32x4 acc[4][4] = {};
    for (int k0 = 0; k0 < Kd; k0 += 32) {
        __syncthreads();
#pragma unroll
        for (int r = 0; r < 2; r++) {
            int row = r * 64 + wv * 16;
            async_ld16(&A[(size_t)(m0 + row + lrow) * Kd + k0 + lcol], &As[row * 32]);
            async_ld16(&Bt[(size_t)(n0 + row + lrow) * Kd + k0 + lcol], &Bs[row * 32]);
        }
        __syncthreads();
        bf16x8 af[4], bfr[4];
#pragma unroll
        for (int i = 0; i < 4; i++)
            af[i] = *(const bf16x8*)(&As[(wm + i * 16 + l16) * 32 + quad * 8]);
#pragma unroll
        for (int j = 0; j < 4; j++)
            bfr[j] = *(const bf16x8*)(&Bs[(wn + j * 16 + l16) * 32 + quad * 8]);
#pragma unroll
        for (int i = 0; i < 4; i++)
#pragma unroll
            for (int j = 0; j < 4; j++)
                acc[i][j] = MFMA16(af[i], bfr[j], acc[i][j]);
    }
#pragma unroll
    for (int i = 0; i < 4; i++) {
#pragma unroll
        for (int j = 0; j < 4; j++) {
            int n = n0 + wn + j * 16 + l16;
            float bv = bias[n];
            int sec = n >> 10, nl = n & 1023;
            int h = nl >> 6, d = nl & 63;
            int mbase = m0 + wm + i * 16 + quad * 4;
            int bb = mbase >> 11, s = mbase & 2047;
            if (sec == 2) {  // V: transposed store [B,H,D,S]
                bf16x4 v4;
#pragma unroll
                for (int r = 0; r < 4; r++) v4[r] = (__bf16)(acc[i][j][r] + bv);
                *(bf16x4*)(&Vo[((size_t)(bb * 16 + h) * 64 + d) * 2048 + s]) = v4;
            } else {
                __bf16* dst = sec == 0 ? Qo : Ko;
                // Q: fold 1/sqrt(64) * log2(e) (attention uses exp2)
                float scl = (sec == 0) ? 0.1803368801f : 1.0f;
#pragma unroll
                for (int r = 0; r < 4; r++)
                    dst[((size_t)(bb * 16 + h) * 2048 + (s + r)) * 64 + d] =
                        (__bf16)((acc[i][j][r] + bv) * scl);
            }
        }
    }
}

// ---------------------------------------------------------------- proj GEMM (64x128 tiles)
__global__ __launch_bounds__(256, 2) void k_gemm_proj(
    const __bf16* __restrict__ A, const __bf16* __restrict__ Bt,
    const float* __restrict__ bias, float* __restrict__ out) {
    __shared__ __bf16 As[64 * 32];
    __shared__ __bf16 Bs[128 * 32];
    const int Kd = 1024;
    int n0 = blockIdx.x * 128, m0 = blockIdx.y * 64;
    int tid = threadIdx.x;
    int wv = tid >> 6, lane = tid & 63;
    int wm = (wv >> 1) * 32, wn = (wv & 1) * 64;
    int quad = lane >> 4, l16 = lane & 15;
    int lrow = lane >> 2, lcol = (lane & 3) * 8;
    f32x4 acc[2][4] = {};
    for (int k0 = 0; k0 < Kd; k0 += 32) {
        __syncthreads();
        async_ld16(&A[(size_t)(m0 + wv * 16 + lrow) * Kd + k0 + lcol], &As[(wv * 16) * 32]);
#pragma unroll
        for (int r = 0; r < 2; r++) {
            int row = r * 64 + wv * 16;
            async_ld16(&Bt[(size_t)(n0 + row + lrow) * Kd + k0 + lcol], &Bs[row * 32]);
        }
        __syncthreads();
        bf16x8 af[2], bfr[4];
#pragma unroll
        for (int i = 0; i < 2; i++)
            af[i] = *(const bf16x8*)(&As[(wm + i * 16 + l16) * 32 + quad * 8]);
#pragma unroll
        for (int j = 0; j < 4; j++)
            bfr[j] = *(const bf16x8*)(&Bs[(wn + j * 16 + l16) * 32 + quad * 8]);
#pragma unroll
        for (int i = 0; i < 2; i++)
#pragma unroll
            for (int j = 0; j < 4; j++)
                acc[i][j] = MFMA16(af[i], bfr[j], acc[i][j]);
    }
#pragma unroll
    for (int i = 0; i < 2; i++) {
#pragma unroll
        for (int j = 0; j < 4; j++) {
            int n = n0 + wn + j * 16 + l16;
            float bv = bias[n];
#pragma unroll
            for (int r = 0; r < 4; r++) {
                int m = m0 + wm + i * 16 + quad * 4 + r;
                out[(size_t)m * 1024 + n] = acc[i][j][r] + bv;
            }
        }
    }
}

// ---------------------------------------------------------------- flash attention
// Max-free associative softmax via exp2 (log2e folded into Q). 128q x 64k tiles;
// k-range chunked <=16 iters; register prefetch of next K/V tile hides global
// latency behind the compute phase. Partials merged by k_attn_combine.
// 24 chunk-slots/bh: slot<8 -> tile t=slot whole range; else paired halves of t=8..15.
__device__ const int ATT_ORDER[24] = {7, 8, 10, 12, 14, 16, 18, 20, 22, 23, 6, 21,
                                      5, 19, 4, 17, 3, 15, 2, 13, 1, 11, 0, 9};

__global__ __launch_bounds__(256, 4) void k_attn(
    const __bf16* __restrict__ Qg, const __bf16* __restrict__ Kg,
    const __bf16* __restrict__ Vtg, __bf16* __restrict__ Op, float* __restrict__ Lp) {
    __shared__ __bf16 Ks[64 * 72];
    __shared__ __bf16 Vt[64 * 72];
    __shared__ __bf16 Ps[128 * 72];
    int bh = blockIdx.x & 31;
    int slot = ATT_ORDER[blockIdx.x >> 5];
    int t, k0, k1;
    if (slot < 8) { t = slot; k0 = 0; k1 = 2 * t + 2; }
    else { int i2 = slot - 8; t = 8 + (i2 >> 1); k0 = (i2 & 1) * 16; k1 = min(k0 + 16, 2 * t + 2); }
    const __bf16* Qp = Qg + (size_t)bh * 2048 * 64;
    const __bf16* Kp = Kg + (size_t)bh * 2048 * 64;
    const __bf16* Vp = Vtg + (size_t)bh * 64 * 2048;
    int tid = threadIdx.x, wv = tid >> 6, lane = tid & 63;
    int quad = lane >> 4, l16 = lane & 15;
    // staging: thread owns one 32B run (2 uint4) of K and of V
    int srow = (tid * 2) >> 3, scc = ((tid * 2) & 7) * 8;

    // Q B-fragments: q-col = t*128 + wv*32 + qn*16 + l16 (loop-invariant)
    bf16x8 qf[2][2];
#pragma unroll
    for (int qn = 0; qn < 2; qn++)
#pragma unroll
        for (int ks = 0; ks < 2; ks++)
            qf[qn][ks] = *(const bf16x8*)(
                &Qp[(size_t)(t * 128 + wv * 32 + qn * 16 + l16) * 64 + ks * 32 + quad * 8]);
    float l_th[2] = {0.f, 0.f};
    f32x4 acc_o[2][4] = {};

    // prologue: stage tile k0
    {
        const uint4* kg = (const uint4*)(&Kp[(size_t)(k0 * 64 + srow) * 64 + scc]);
        const uint4* vg = (const uint4*)(&Vp[(size_t)srow * 2048 + k0 * 64 + scc]);
        uint4 a = kg[0], bq = kg[1], x = vg[0], y = vg[1];
        *(uint4*)(&Ks[srow * 72 + scc]) = a;
        *(uint4*)(&Ks[srow * 72 + scc + 8]) = bq;
        *(uint4*)(&Vt[srow * 72 + scc]) = x;
        *(uint4*)(&Vt[srow * 72 + scc + 8]) = y;
    }
    __syncthreads();

    for (int kt = k0; kt < k1; kt++) {
        bool more = (kt + 1 < k1);  // block-uniform
        uint4 pk0, pk1, pv0, pv1;
        if (more) {  // prefetch next tile into registers; vmcnt waits after compute
            const uint4* kg = (const uint4*)(&Kp[(size_t)((kt + 1) * 64 + srow) * 64 + scc]);
            const uint4* vg = (const uint4*)(&Vp[(size_t)srow * 2048 + (kt + 1) * 64 + scc]);
            pk0 = kg[0]; pk1 = kg[1]; pv0 = vg[0]; pv1 = vg[1];
        }
        // S^T: rows = 64 k (i*16+quad*4+r), cols = q (wv*32+qn*16+l16)
        f32x4 s[2][4] = {};
#pragma unroll
        for (int ks = 0; ks < 2; ks++) {
            bf16x8 kf[4];
#pragma unroll
            for (int i = 0; i < 4; i++)
                kf[i] = *(const bf16x8*)(&Ks[(i * 16 + l16) * 72 + ks * 32 + quad * 8]);
#pragma unroll
            for (int i = 0; i < 4; i++)
#pragma unroll
                for (int qn = 0; qn < 2; qn++)
                    s[qn][i] = MFMA16(kf[i], qf[qn][ks], s[qn][i]);
        }
        // causal mask (elementwise only where the tile straddles the diagonal)
#pragma unroll
        for (int qn = 0; qn < 2; qn++) {
            int qmin = t * 128 + wv * 32 + qn * 16;
            if (kt * 64 + 63 > qmin) {
#pragma unroll
                for (int i = 0; i < 4; i++)
#pragma unroll
                    for (int r = 0; r < 4; r++)
                        if (kt * 64 + i * 16 + quad * 4 + r > qmin + l16) s[qn][i][r] = -1e30f;
            }
        }
        // exp2 (no max subtraction) + per-thread l accumulation + P write
#pragma unroll
        for (int qn = 0; qn < 2; qn++)
#pragma unroll
            for (int i = 0; i < 4; i++) {
                bf16x4 pk;
#pragma unroll
                for (int r = 0; r < 4; r++) {
                    float p = exp2f(s[qn][i][r]);
                    l_th[qn] += p;
                    pk[r] = (__bf16)p;
                }
                *(bf16x4*)(&Ps[(wv * 32 + qn * 16 + l16) * 72 + i * 16 + quad * 4]) = pk;
            }
        // O^T += V^T P^T (P is wave-private band; lgkmcnt orders write->read)
#pragma unroll
        for (int ks = 0; ks < 2; ks++) {
            bf16x8 pf[2];
#pragma unroll
            for (int qn = 0; qn < 2; qn++)
                pf[qn] = *(const bf16x8*)(
                    &Ps[(wv * 32 + qn * 16 + l16) * 72 + ks * 32 + quad * 8]);
            bf16x8 vf[4];
#pragma unroll
            for (int i = 0; i < 4; i++)
                vf[i] = *(const bf16x8*)(&Vt[(i * 16 + l16) * 72 + ks * 32 + quad * 8]);
#pragma unroll
            for (int i = 0; i < 4; i++)
#pragma unroll
                for (int qn = 0; qn < 2; qn++)
                    acc_o[qn][i] = MFMA16(vf[i], pf[qn], acc_o[qn][i]);
        }
        if (more) {
            __syncthreads();  // all reads of Ks/Vt done
            *(uint4*)(&Ks[srow * 72 + scc]) = pk0;
            *(uint4*)(&Ks[srow * 72 + scc + 8]) = pk1;
            *(uint4*)(&Vt[srow * 72 + scc]) = pv0;
            *(uint4*)(&Vt[srow * 72 + scc + 8]) = pv1;
            __syncthreads();
        }
    }
    // epilogue: partial (unnormalized O, l) for this chunk
    size_t pbase = (size_t)slot * 32 + bh;
#pragma unroll
    for (int qn = 0; qn < 2; qn++) {
        float ls = l_th[qn];
        ls += __shfl_xor(ls, 16);
        ls += __shfl_xor(ls, 32);
        int ql = wv * 32 + qn * 16 + l16;
        if (quad == 0) Lp[pbase * 128 + ql] = ls;
#pragma unroll
        for (int i = 0; i < 4; i++) {
            bf16x4 o4;
#pragma unroll
            for (int r = 0; r < 4; r++) o4[r] = (__bf16)acc_o[qn][i][r];
            *(bf16x4*)(&Op[(pbase * 128 + ql) * 64 + i * 16 + quad * 4]) = o4;
        }
    }
}

// Merge <=2 chunk partials per q-row, normalize, write AOb [B,S,E] bf16.
__global__ __launch_bounds__(256) void k_attn_combine(
    const __bf16* __restrict__ Op, const float* __restrict__ Lp,
    __bf16* __restrict__ AOb) {
    int gid = blockIdx.x * 256 + threadIdx.x;  // 32*2048*16 threads
    int d4 = gid & 15;
    int q = (gid >> 4) & 2047;
    int bh = gid >> 15;
    int t = q >> 7, ql = q & 127;
    int n = (t <= 7) ? 1 : 2;
    int base = (t <= 7) ? t : 8 + 2 * (t - 8);
    float L = 0.f, o[4] = {};
    for (int c = 0; c < n; c++) {
        size_t idx = (size_t)(base + c) * 32 + bh;
        L += Lp[idx * 128 + ql];
        bf16x4 p4 = *(const bf16x4*)(&Op[(idx * 128 + ql) * 64 + d4 * 4]);
#pragma unroll
        for (int r = 0; r < 4; r++) o[r] += (float)p4[r];
    }
    float inv = 1.f / L;
    int b = bh >> 4, h = bh & 15;
    bf16x4 o4;
#pragma unroll
    for (int r = 0; r < 4; r++) o4[r] = (__bf16)(o[r] * inv);
    *(bf16x4*)(&AOb[((size_t)b * 2048 + q) * 1024 + h * 64 + d4 * 4]) = o4;
}

// ---------------------------------------------------------------- launch
extern "C" void kernel_launch(void* const* d_in, const int* in_sizes, int n_in,
                              void* d_out, int out_size, void* d_ws, size_t ws_size,
                              hipStream_t stream) {
    const float* hs = (const float*)d_in[0];
    const float* w1 = (const float*)d_in[1];
    const float* b1 = (const float*)d_in[2];
    const float* w2 = (const float*)d_in[3];
    const float* b2 = (const float*)d_in[4];
    float* out = (float*)d_out;

    char* ws = (char*)d_ws;
    __bf16* hsb = (__bf16*)(ws);                               // [0,8M), dead after qkv
    __bf16* w1t = (__bf16*)(ws + (size_t)8 * 1024 * 1024);     // [8,14M), dead after qkv
    __bf16* w2t = (__bf16*)(ws + (size_t)14 * 1024 * 1024);    // [14,16M)
    __bf16* Qb  = (__bf16*)(ws + (size_t)16 * 1024 * 1024);    // [16,24M) [B,H,S,D]
    __bf16* Kb  = (__bf16*)(ws + (size_t)24 * 1024 * 1024);    // [24,32M) [B,H,S,D]
    __bf16* Vb  = (__bf16*)(ws + (size_t)32 * 1024 * 1024);    // [32,40M) [B,H,D,S]
    __bf16* AOb = (__bf16*)(ws + (size_t)40 * 1024 * 1024);    // [40,48M) [B,S,E]
    __bf16* Opart = (__bf16*)(ws);                             // [0,12M) overlays hsb/w1t
    float*  Lpart = (float*)(ws + (size_t)13 * 1024 * 1024);   // [13,13.4M)

    k_prep<<<8192, 256, 0, stream>>>(hs, w1, w2, hsb, w1t, w2t);
    k_gemm_qkv<<<dim3(24, 32), 256, 0, stream>>>(hsb, w1t, b1, Qb, Kb, Vb);
    k_attn<<<768, 256, 0, stream>>>(Qb, Kb, Vb, Opart, Lpart);
    k_attn_combine<<<4096, 256, 0, stream>>>(Opart, Lpart, AOb);
    k_gemm_proj<<<dim3(8, 64), 256, 0, stream>>>(AOb, w2t, b2, out);
}

// Round 11
// 185.576 us; speedup vs baseline: 1.0980x; 1.0980x over previous
//
#include <hip/hip_runtime.h>
#include <stdint.h>

typedef __attribute__((ext_vector_type(8))) __bf16 bf16x8;
typedef __attribute__((ext_vector_type(4))) __bf16 bf16x4;
typedef __attribute__((ext_vector_type(4))) float f32x4;

#define MFMA16(a, b, c) __builtin_amdgcn_mfma_f32_16x16x32_bf16(a, b, c, 0, 0, 0)

// async 16B global->LDS: lds dest must be wave-uniform base; lane writes at base+lane*16
__device__ __forceinline__ void async_ld16(const __bf16* g, __bf16* lds_base) {
    __builtin_amdgcn_global_load_lds(
        (const __attribute__((address_space(1))) void*)g,
        (__attribute__((address_space(3))) void*)lds_base, 16, 0, 0);
}

// ---------------------------------------------------------------- fused prep
// bid < 4096:            cast hs fp32 -> bf16 (4M elems)
// 4096 <= bid < 7168:    transpose-cast w1 [1024,3072] -> w1t [3072,1024]
// bid >= 7168:           transpose-cast w2 [1024,1024] -> w2t [1024,1024]
__global__ __launch_bounds__(256) void k_prep(
    const float* __restrict__ hs, const float* __restrict__ w1,
    const float* __restrict__ w2, __bf16* __restrict__ hsb,
    __bf16* __restrict__ w1t, __bf16* __restrict__ w2t) {
    __shared__ __bf16 tile[32][33];
    int bid = blockIdx.x, tid = threadIdx.x;
    if (bid < 4096) {
        int i = (bid * 256 + tid) * 4;
        float4 v = *(const float4*)(hs + i);
        bf16x4 o;
        o.x = (__bf16)v.x; o.y = (__bf16)v.y; o.z = (__bf16)v.z; o.w = (__bf16)v.w;
        *(bf16x4*)(hsb + i) = o;
        return;
    }
    const float* in; __bf16* out; int C, tb;
    if (bid < 7168) { in = w1; out = w1t; C = 3072; tb = bid - 4096; }
    else            { in = w2; out = w2t; C = 1024; tb = bid - 7168; }
    const int R = 1024;
    int ntc = C >> 5;
    int c0 = (tb % ntc) * 32, r0 = (tb / ntc) * 32;
    int tx = tid & 31, ty = tid >> 5;  // 32 x 8
#pragma unroll
    for (int i = 0; i < 4; i++)
        tile[ty + i * 8][tx] = (__bf16)in[(size_t)(r0 + ty + i * 8) * C + c0 + tx];
    __syncthreads();
#pragma unroll
    for (int i = 0; i < 4; i++)
        out[(size_t)(c0 + ty + i * 8) * R + r0 + tx] = tile[tx][ty + i * 8];
}

// ---------------------------------------------------------------- QKV GEMM (m97-style)
__global__ __launch_bounds__(256, 2) void k_gemm_qkv(
    const __bf16* __restrict__ A, const __bf16* __restrict__ Bt,
    const float* __restrict__ bias,
    __bf16* __restrict__ Qo, __bf16* __restrict__ Ko, __bf16* __restrict__ Vo) {
    __shared__ __bf16 As[128 * 32];
    __shared__ __bf16 Bs[128 * 32];
    const int Kd = 1024;
    int n0 = blockIdx.x * 128, m0 = blockIdx.y * 128;
    int tid = threadIdx.x;
    int wv = tid >> 6, lane = tid & 63;
    int wm = (wv >> 1) * 64, wn = (wv & 1) * 64;
    int quad = lane >> 4, l16 = lane & 15;
    int lrow = lane >> 2, lcol = (lane & 3) * 8;
    f32x4 acc[4][4] = {};
    for (int k0 = 0; k0 < Kd; k0 += 32) {
        __syncthreads();
#pragma unroll
        for (int r = 0; r < 2; r++) {
            int row = r * 64 + wv * 16;
            async_ld16(&A[(size_t)(m0 + row + lrow) * Kd + k0 + lcol], &As[row * 32]);
            async_ld16(&Bt[(size_t)(n0 + row + lrow) * Kd + k0 + lcol], &Bs[row * 32]);
        }
        __syncthreads();
        bf16x8 af[4], bfr[4];
#pragma unroll
        for (int i = 0; i < 4; i++)
            af[i] = *(const bf16x8*)(&As[(wm + i * 16 + l16) * 32 + quad * 8]);
#pragma unroll
        for (int j = 0; j < 4; j++)
            bfr[j] = *(const bf16x8*)(&Bs[(wn + j * 16 + l16) * 32 + quad * 8]);
#pragma unroll
        for (int i = 0; i < 4; i++)
#pragma unroll
            for (int j = 0; j < 4; j++)
                acc[i][j] = MFMA16(af[i], bfr[j], acc[i][j]);
    }
#pragma unroll
    for (int i = 0; i < 4; i++) {
#pragma unroll
        for (int j = 0; j < 4; j++) {
            int n = n0 + wn + j * 16 + l16;
            float bv = bias[n];
            int sec = n >> 10, nl = n & 1023;
            int h = nl >> 6, d = nl & 63;
            int mbase = m0 + wm + i * 16 + quad * 4;
            int bb = mbase >> 11, s = mbase & 2047;
            if (sec == 2) {  // V: transposed store [B,H,D,S]
                bf16x4 v4;
#pragma unroll
                for (int r = 0; r < 4; r++) v4[r] = (__bf16)(acc[i][j][r] + bv);
                *(bf16x4*)(&Vo[((size_t)(bb * 16 + h) * 64 + d) * 2048 + s]) = v4;
            } else {
                __bf16* dst = sec == 0 ? Qo : Ko;
                // Q: fold 1/sqrt(64) * log2(e) (attention uses exp2)
                float scl = (sec == 0) ? 0.1803368801f : 1.0f;
#pragma unroll
                for (int r = 0; r < 4; r++)
                    dst[((size_t)(bb * 16 + h) * 2048 + (s + r)) * 64 + d] =
                        (__bf16)((acc[i][j][r] + bv) * scl);
            }
        }
    }
}

// ---------------------------------------------------------------- proj GEMM (64x128 tiles)
__global__ __launch_bounds__(256, 2) void k_gemm_proj(
    const __bf16* __restrict__ A, const __bf16* __restrict__ Bt,
    const float* __restrict__ bias, float* __restrict__ out) {
    __shared__ __bf16 As[64 * 32];
    __shared__ __bf16 Bs[128 * 32];
    const int Kd = 1024;
    int n0 = blockIdx.x * 128, m0 = blockIdx.y * 64;
    int tid = threadIdx.x;
    int wv = tid >> 6, lane = tid & 63;
    int wm = (wv >> 1) * 32, wn = (wv & 1) * 64;
    int quad = lane >> 4, l16 = lane & 15;
    int lrow = lane >> 2, lcol = (lane & 3) * 8;
    f32x4 acc[2][4] = {};
    for (int k0 = 0; k0 < Kd; k0 += 32) {
        __syncthreads();
        async_ld16(&A[(size_t)(m0 + wv * 16 + lrow) * Kd + k0 + lcol], &As[(wv * 16) * 32]);
#pragma unroll
        for (int r = 0; r < 2; r++) {
            int row = r * 64 + wv * 16;
            async_ld16(&Bt[(size_t)(n0 + row + lrow) * Kd + k0 + lcol], &Bs[row * 32]);
        }
        __syncthreads();
        bf16x8 af[2], bfr[4];
#pragma unroll
        for (int i = 0; i < 2; i++)
            af[i] = *(const bf16x8*)(&As[(wm + i * 16 + l16) * 32 + quad * 8]);
#pragma unroll
        for (int j = 0; j < 4; j++)
            bfr[j] = *(const bf16x8*)(&Bs[(wn + j * 16 + l16) * 32 + quad * 8]);
#pragma unroll
        for (int i = 0; i < 2; i++)
#pragma unroll
            for (int j = 0; j < 4; j++)
                acc[i][j] = MFMA16(af[i], bfr[j], acc[i][j]);
    }
#pragma unroll
    for (int i = 0; i < 2; i++) {
#pragma unroll
        for (int j = 0; j < 4; j++) {
            int n = n0 + wn + j * 16 + l16;
            float bv = bias[n];
#pragma unroll
            for (int r = 0; r < 4; r++) {
                int m = m0 + wm + i * 16 + quad * 4 + r;
                out[(size_t)m * 1024 + n] = acc[i][j][r] + bv;
            }
        }
    }
}

// ---------------------------------------------------------------- flash attention
// Max-free associative softmax via exp2 (log2e folded into Q). 128q x 64k tiles;
// k-range chunked <=16 iters; two-barrier staging (register prefetch REGRESSED:
// R10 showed scratch spill, WRITE_SIZE 15->47 MB). Partials merged by combine.
// 24 chunk-slots/bh: slot<8 -> tile t=slot whole range; else paired halves of t=8..15.
__device__ const int ATT_ORDER[24] = {7, 8, 10, 12, 14, 16, 18, 20, 22, 23, 6, 21,
                                      5, 19, 4, 17, 3, 15, 2, 13, 1, 11, 0, 9};

__global__ __launch_bounds__(256, 4) void k_attn(
    const __bf16* __restrict__ Qg, const __bf16* __restrict__ Kg,
    const __bf16* __restrict__ Vtg, __bf16* __restrict__ Op, float* __restrict__ Lp) {
    __shared__ __bf16 Ks[64 * 72];
    __shared__ __bf16 Vt[64 * 72];
    __shared__ __bf16 Ps[128 * 72];
    int bh = blockIdx.x & 31;
    int slot = ATT_ORDER[blockIdx.x >> 5];
    int t, k0, k1;
    if (slot < 8) { t = slot; k0 = 0; k1 = 2 * t + 2; }
    else { int i2 = slot - 8; t = 8 + (i2 >> 1); k0 = (i2 & 1) * 16; k1 = min(k0 + 16, 2 * t + 2); }
    const __bf16* Qp = Qg + (size_t)bh * 2048 * 64;
    const __bf16* Kp = Kg + (size_t)bh * 2048 * 64;
    const __bf16* Vp = Vtg + (size_t)bh * 64 * 2048;
    int tid = threadIdx.x, wv = tid >> 6, lane = tid & 63;
    int quad = lane >> 4, l16 = lane & 15;

    // Q B-fragments: q-col = t*128 + wv*32 + qn*16 + l16 (loop-invariant)
    bf16x8 qf[2][2];
#pragma unroll
    for (int qn = 0; qn < 2; qn++)
#pragma unroll
        for (int ks = 0; ks < 2; ks++)
            qf[qn][ks] = *(const bf16x8*)(
                &Qp[(size_t)(t * 128 + wv * 32 + qn * 16 + l16) * 64 + ks * 32 + quad * 8]);
    float l_th[2] = {0.f, 0.f};
    f32x4 acc_o[2][4] = {};

    for (int kt = k0; kt < k1; kt++) {
        __syncthreads();  // prior-iter Ks/Vt reads done before restaging
#pragma unroll
        for (int it = 0; it < 2; it++) {
            int idx = tid * 2 + it;
            int row = idx >> 3, cc = (idx & 7) * 8;
            *(uint4*)(&Ks[row * 72 + cc]) =
                *(const uint4*)(&Kp[(size_t)(kt * 64 + row) * 64 + cc]);
            *(uint4*)(&Vt[row * 72 + cc]) =
                *(const uint4*)(&Vp[(size_t)row * 2048 + kt * 64 + cc]);
        }
        __syncthreads();
        // S^T: rows = 64 k (i*16+quad*4+r), cols = q (wv*32+qn*16+l16)
        f32x4 s[2][4] = {};
#pragma unroll
        for (int ks = 0; ks < 2; ks++) {
            bf16x8 kf[4];
#pragma unroll
            for (int i = 0; i < 4; i++)
                kf[i] = *(const bf16x8*)(&Ks[(i * 16 + l16) * 72 + ks * 32 + quad * 8]);
#pragma unroll
            for (int i = 0; i < 4; i++)
#pragma unroll
                for (int qn = 0; qn < 2; qn++)
                    s[qn][i] = MFMA16(kf[i], qf[qn][ks], s[qn][i]);
        }
        // causal mask (elementwise only where the tile straddles the diagonal)
#pragma unroll
        for (int qn = 0; qn < 2; qn++) {
            int qmin = t * 128 + wv * 32 + qn * 16;
            if (kt * 64 + 63 > qmin) {
#pragma unroll
                for (int i = 0; i < 4; i++)
#pragma unroll
                    for (int r = 0; r < 4; r++)
                        if (kt * 64 + i * 16 + quad * 4 + r > qmin + l16) s[qn][i][r] = -1e30f;
            }
        }
        // exp2 (no max subtraction) + per-thread l accumulation + P write
#pragma unroll
        for (int qn = 0; qn < 2; qn++)
#pragma unroll
            for (int i = 0; i < 4; i++) {
                bf16x4 pk;
#pragma unroll
                for (int r = 0; r < 4; r++) {
                    float p = exp2f(s[qn][i][r]);
                    l_th[qn] += p;
                    pk[r] = (__bf16)p;
                }
                *(bf16x4*)(&Ps[(wv * 32 + qn * 16 + l16) * 72 + i * 16 + quad * 4]) = pk;
            }
        // O^T += V^T P^T (P is wave-private band; lgkmcnt orders write->read)
#pragma unroll
        for (int ks = 0; ks < 2; ks++) {
            bf16x8 pf[2];
#pragma unroll
            for (int qn = 0; qn < 2; qn++)
                pf[qn] = *(const bf16x8*)(
                    &Ps[(wv * 32 + qn * 16 + l16) * 72 + ks * 32 + quad * 8]);
            bf16x8 vf[4];
#pragma unroll
            for (int i = 0; i < 4; i++)
                vf[i] = *(const bf16x8*)(&Vt[(i * 16 + l16) * 72 + ks * 32 + quad * 8]);
#pragma unroll
            for (int i = 0; i < 4; i++)
#pragma unroll
                for (int qn = 0; qn < 2; qn++)
                    acc_o[qn][i] = MFMA16(vf[i], pf[qn], acc_o[qn][i]);
        }
    }
    // epilogue: partial (unnormalized O, l) for this chunk
    size_t pbase = (size_t)slot * 32 + bh;
#pragma unroll
    for (int qn = 0; qn < 2; qn++) {
        float ls = l_th[qn];
        ls += __shfl_xor(ls, 16);
        ls += __shfl_xor(ls, 32);
        int ql = wv * 32 + qn * 16 + l16;
        if (quad == 0) Lp[pbase * 128 + ql] = ls;
#pragma unroll
        for (int i = 0; i < 4; i++) {
            bf16x4 o4;
#pragma unroll
            for (int r = 0; r < 4; r++) o4[r] = (__bf16)acc_o[qn][i][r];
            *(bf16x4*)(&Op[(pbase * 128 + ql) * 64 + i * 16 + quad * 4]) = o4;
        }
    }
}

// Merge <=2 chunk partials per q-row, normalize, write AOb [B,S,E] bf16.
__global__ __launch_bounds__(256) void k_attn_combine(
    const __bf16* __restrict__ Op, const float* __restrict__ Lp,
    __bf16* __restrict__ AOb) {
    int gid = blockIdx.x * 256 + threadIdx.x;  // 32*2048*16 threads
    int d4 = gid & 15;
    int q = (gid >> 4) & 2047;
    int bh = gid >> 15;
    int t = q >> 7, ql = q & 127;
    int n = (t <= 7) ? 1 : 2;
    int base = (t <= 7) ? t : 8 + 2 * (t - 8);
    float L = 0.f, o[4] = {};
    for (int c = 0; c < n; c++) {
        size_t idx = (size_t)(base + c) * 32 + bh;
        L += Lp[idx * 128 + ql];
        bf16x4 p4 = *(const bf16x4*)(&Op[(idx * 128 + ql) * 64 + d4 * 4]);
#pragma unroll
        for (int r = 0; r < 4; r++) o[r] += (float)p4[r];
    }
    float inv = 1.f / L;
    int b = bh >> 4, h = bh & 15;
    bf16x4 o4;
#pragma unroll
    for (int r = 0; r < 4; r++) o4[r] = (__bf16)(o[r] * inv);
    *(bf16x4*)(&AOb[((size_t)b * 2048 + q) * 1024 + h * 64 + d4 * 4]) = o4;
}

// ---------------------------------------------------------------- launch
extern "C" void kernel_launch(void* const* d_in, const int* in_sizes, int n_in,
                              void* d_out, int out_size, void* d_ws, size_t ws_size,
                              hipStream_t stream) {
    const float* hs = (const float*)d_in[0];
    const float* w1 = (const float*)d_in[1];
    const float* b1 = (const float*)d_in[2];
    const float* w2 = (const float*)d_in[3];
    const float* b2 = (const float*)d_in[4];
    float* out = (float*)d_out;

    char* ws = (char*)d_ws;
    __bf16* hsb = (__bf16*)(ws);                               // [0,8M), dead after qkv
    __bf16* w1t = (__bf16*)(ws + (size_t)8 * 1024 * 1024);     // [8,14M), dead after qkv
    __bf16* w2t = (__bf16*)(ws + (size_t)14 * 1024 * 1024);    // [14,16M)
    __bf16* Qb  = (__bf16*)(ws + (size_t)16 * 1024 * 1024);    // [16,24M) [B,H,S,D]
    __bf16* Kb  = (__bf16*)(ws + (size_t)24 * 1024 * 1024);    // [24,32M) [B,H,S,D]
    __bf16* Vb  = (__bf16*)(ws + (size_t)32 * 1024 * 1024);    // [32,40M) [B,H,D,S]
    __bf16* AOb = (__bf16*)(ws + (size_t)40 * 1024 * 1024);    // [40,48M) [B,S,E]
    __bf16* Opart = (__bf16*)(ws);                             // [0,12.6M) overlays hsb/w1t
    float*  Lpart = (float*)(ws + (size_t)13 * 1024 * 1024);   // [13,13.4M)

    k_prep<<<8192, 256, 0, stream>>>(hs, w1, w2, hsb, w1t, w2t);
    k_gemm_qkv<<<dim3(24, 32), 256, 0, stream>>>(hsb, w1t, b1, Qb, Kb, Vb);
    k_attn<<<768, 256, 0, stream>>>(Qb, Kb, Vb, Opart, Lpart);
    k_attn_combine<<<4096, 256, 0, stream>>>(Opart, Lpart, AOb);
    k_gemm_proj<<<dim3(8, 64), 256, 0, stream>>>(AOb, w2t, b2, out);
}

// Round 12
// 184.006 us; speedup vs baseline: 1.1073x; 1.0085x over previous
//
#include <hip/hip_runtime.h>
#include <stdint.h>

typedef __attribute__((ext_vector_type(8))) __bf16 bf16x8;
typedef __attribute__((ext_vector_type(4))) __bf16 bf16x4;
typedef __attribute__((ext_vector_type(4))) float f32x4;

#define MFMA16(a, b, c) __builtin_amdgcn_mfma_f32_16x16x32_bf16(a, b, c, 0, 0, 0)

// async 16B global->LDS: lds dest must be wave-uniform base; lane writes at base+lane*16
__device__ __forceinline__ void async_ld16(const __bf16* g, __bf16* lds_base) {
    __builtin_amdgcn_global_load_lds(
        (const __attribute__((address_space(1))) void*)g,
        (__attribute__((address_space(3))) void*)lds_base, 16, 0, 0);
}

// ---------------------------------------------------------------- fused prep
// bid < 4096:            cast hs fp32 -> bf16 (4M elems)
// 4096 <= bid < 7168:    transpose-cast w1 [1024,3072] -> w1t [3072,1024]
// bid >= 7168:           transpose-cast w2 [1024,1024] -> w2t [1024,1024]
__global__ __launch_bounds__(256) void k_prep(
    const float* __restrict__ hs, const float* __restrict__ w1,
    const float* __restrict__ w2, __bf16* __restrict__ hsb,
    __bf16* __restrict__ w1t, __bf16* __restrict__ w2t) {
    __shared__ __bf16 tile[32][33];
    int bid = blockIdx.x, tid = threadIdx.x;
    if (bid < 4096) {
        int i = (bid * 256 + tid) * 4;
        float4 v = *(const float4*)(hs + i);
        bf16x4 o;
        o.x = (__bf16)v.x; o.y = (__bf16)v.y; o.z = (__bf16)v.z; o.w = (__bf16)v.w;
        *(bf16x4*)(hsb + i) = o;
        return;
    }
    const float* in; __bf16* out; int C, tb;
    if (bid < 7168) { in = w1; out = w1t; C = 3072; tb = bid - 4096; }
    else            { in = w2; out = w2t; C = 1024; tb = bid - 7168; }
    const int R = 1024;
    int ntc = C >> 5;
    int c0 = (tb % ntc) * 32, r0 = (tb / ntc) * 32;
    int tx = tid & 31, ty = tid >> 5;  // 32 x 8
#pragma unroll
    for (int i = 0; i < 4; i++)
        tile[ty + i * 8][tx] = (__bf16)in[(size_t)(r0 + ty + i * 8) * C + c0 + tx];
    __syncthreads();
#pragma unroll
    for (int i = 0; i < 4; i++)
        out[(size_t)(c0 + ty + i * 8) * R + r0 + tx] = tile[tx][ty + i * 8];
}

// ---------------------------------------------------------------- QKV GEMM (m97-style)
__global__ __launch_bounds__(256, 2) void k_gemm_qkv(
    const __bf16* __restrict__ A, const __bf16* __restrict__ Bt,
    const float* __restrict__ bias,
    __bf16* __restrict__ Qo, __bf16* __restrict__ Ko, __bf16* __restrict__ Vo) {
    __shared__ __bf16 As[128 * 32];
    __shared__ __bf16 Bs[128 * 32];
    const int Kd = 1024;
    int n0 = blockIdx.x * 128, m0 = blockIdx.y * 128;
    int tid = threadIdx.x;
    int wv = tid >> 6, lane = tid & 63;
    int wm = (wv >> 1) * 64, wn = (wv & 1) * 64;
    int quad = lane >> 4, l16 = lane & 15;
    int lrow = lane >> 2, lcol = (lane & 3) * 8;
    f32x4 acc[4][4] = {};
    for (int k0 = 0; k0 < Kd; k0 += 32) {
        __syncthreads();
#pragma unroll
        for (int r = 0; r < 2; r++) {
            int row = r * 64 + wv * 16;
            async_ld16(&A[(size_t)(m0 + row + lrow) * Kd + k0 + lcol], &As[row * 32]);
            async_ld16(&Bt[(size_t)(n0 + row + lrow) * Kd + k0 + lcol], &Bs[row * 32]);
        }
        __syncthreads();
        bf16x8 af[4], bfr[4];
#pragma unroll
        for (int i = 0; i < 4; i++)
            af[i] = *(const bf16x8*)(&As[(wm + i * 16 + l16) * 32 + quad * 8]);
#pragma unroll
        for (int j = 0; j < 4; j++)
            bfr[j] = *(const bf16x8*)(&Bs[(wn + j * 16 + l16) * 32 + quad * 8]);
#pragma unroll
        for (int i = 0; i < 4; i++)
#pragma unroll
            for (int j = 0; j < 4; j++)
                acc[i][j] = MFMA16(af[i], bfr[j], acc[i][j]);
    }
#pragma unroll
    for (int i = 0; i < 4; i++) {
#pragma unroll
        for (int j = 0; j < 4; j++) {
            int n = n0 + wn + j * 16 + l16;
            float bv = bias[n];
            int sec = n >> 10, nl = n & 1023;
            int h = nl >> 6, d = nl & 63;
            int mbase = m0 + wm + i * 16 + quad * 4;
            int bb = mbase >> 11, s = mbase & 2047;
            if (sec == 2) {  // V: transposed store [B,H,D,S]
                bf16x4 v4;
#pragma unroll
                for (int r = 0; r < 4; r++) v4[r] = (__bf16)(acc[i][j][r] + bv);
                *(bf16x4*)(&Vo[((size_t)(bb * 16 + h) * 64 + d) * 2048 + s]) = v4;
            } else {
                __bf16* dst = sec == 0 ? Qo : Ko;
                // Q: fold 1/sqrt(64) * log2(e) (attention uses exp2)
                float scl = (sec == 0) ? 0.1803368801f : 1.0f;
#pragma unroll
                for (int r = 0; r < 4; r++)
                    dst[((size_t)(bb * 16 + h) * 2048 + (s + r)) * 64 + d] =
                        (__bf16)((acc[i][j][r] + bv) * scl);
            }
        }
    }
}

// ---------------------------------------------------------------- proj GEMM (64x128 tiles)
__global__ __launch_bounds__(256, 2) void k_gemm_proj(
    const __bf16* __restrict__ A, const __bf16* __restrict__ Bt,
    const float* __restrict__ bias, float* __restrict__ out) {
    __shared__ __bf16 As[64 * 32];
    __shared__ __bf16 Bs[128 * 32];
    const int Kd = 1024;
    int n0 = blockIdx.x * 128, m0 = blockIdx.y * 64;
    int tid = threadIdx.x;
    int wv = tid >> 6, lane = tid & 63;
    int wm = (wv >> 1) * 32, wn = (wv & 1) * 64;
    int quad = lane >> 4, l16 = lane & 15;
    int lrow = lane >> 2, lcol = (lane & 3) * 8;
    f32x4 acc[2][4] = {};
    for (int k0 = 0; k0 < Kd; k0 += 32) {
        __syncthreads();
        async_ld16(&A[(size_t)(m0 + wv * 16 + lrow) * Kd + k0 + lcol], &As[(wv * 16) * 32]);
#pragma unroll
        for (int r = 0; r < 2; r++) {
            int row = r * 64 + wv * 16;
            async_ld16(&Bt[(size_t)(n0 + row + lrow) * Kd + k0 + lcol], &Bs[row * 32]);
        }
        __syncthreads();
        bf16x8 af[2], bfr[4];
#pragma unroll
        for (int i = 0; i < 2; i++)
            af[i] = *(const bf16x8*)(&As[(wm + i * 16 + l16) * 32 + quad * 8]);
#pragma unroll
        for (int j = 0; j < 4; j++)
            bfr[j] = *(const bf16x8*)(&Bs[(wn + j * 16 + l16) * 32 + quad * 8]);
#pragma unroll
        for (int i = 0; i < 2; i++)
#pragma unroll
            for (int j = 0; j < 4; j++)
                acc[i][j] = MFMA16(af[i], bfr[j], acc[i][j]);
    }
#pragma unroll
    for (int i = 0; i < 2; i++) {
#pragma unroll
        for (int j = 0; j < 4; j++) {
            int n = n0 + wn + j * 16 + l16;
            float bv = bias[n];
#pragma unroll
            for (int r = 0; r < 4; r++) {
                int m = m0 + wm + i * 16 + quad * 4 + r;
                out[(size_t)m * 1024 + n] = acc[i][j][r] + bv;
            }
        }
    }
}

// ---------------------------------------------------------------- flash attention
// Max-free associative softmax via exp2 (log2e folded into Q). 128q x 64k tiles;
// k-range chunked <=16 iters. K/V staged via global_load_lds DOUBLE BUFFER
// (register-free async DMA; loads issued at iter start, drained by the single
// end-of-iter barrier -> global latency fully off the serial chain).
// LDS rows unpadded (required by global_load_lds); bank conflicts broken by
// XOR swizzle: LDS slot (r,j) holds global 16B-chunk (r, j^(r&7)).
// 24 chunk-slots/bh: slot<8 -> tile t=slot whole range; else paired halves of t=8..15.
__device__ const int ATT_ORDER[24] = {7, 8, 10, 12, 14, 16, 18, 20, 22, 23, 6, 21,
                                      5, 19, 4, 17, 3, 15, 2, 13, 1, 11, 0, 9};

__global__ __launch_bounds__(256, 3) void k_attn(
    const __bf16* __restrict__ Qg, const __bf16* __restrict__ Kg,
    const __bf16* __restrict__ Vtg, __bf16* __restrict__ Op, float* __restrict__ Lp) {
    __shared__ __bf16 Ksb[2][64 * 64];
    __shared__ __bf16 Vtb[2][64 * 64];
    __shared__ __bf16 Ps[128 * 72];
    int bh = blockIdx.x & 31;
    int slot = ATT_ORDER[blockIdx.x >> 5];
    int t, k0, k1;
    if (slot < 8) { t = slot; k0 = 0; k1 = 2 * t + 2; }
    else { int i2 = slot - 8; t = 8 + (i2 >> 1); k0 = (i2 & 1) * 16; k1 = min(k0 + 16, 2 * t + 2); }
    const __bf16* Qp = Qg + (size_t)bh * 2048 * 64;
    const __bf16* Kp = Kg + (size_t)bh * 2048 * 64;
    const __bf16* Vp = Vtg + (size_t)bh * 64 * 2048;
    int tid = threadIdx.x, wv = tid >> 6, lane = tid & 63;
    int quad = lane >> 4, l16 = lane & 15;
    int rl = lane >> 3, sj = lane & 7;        // staging: 8 rows x 8 chunks per call
    int sgo = (sj ^ rl) << 3;                 // swizzled global chunk offset (elems)
    int swl = l16 & 7;                        // fragment-read swizzle key

    // Q B-fragments: q-col = t*128 + wv*32 + qn*16 + l16 (loop-invariant)
    bf16x8 qf[2][2];
#pragma unroll
    for (int qn = 0; qn < 2; qn++)
#pragma unroll
        for (int ks = 0; ks < 2; ks++)
            qf[qn][ks] = *(const bf16x8*)(
                &Qp[(size_t)(t * 128 + wv * 32 + qn * 16 + l16) * 64 + ks * 32 + quad * 8]);
    float l_th[2] = {0.f, 0.f};
    f32x4 acc_o[2][4] = {};

    // async stage of one 64x64 K tile + V tile into buffer `buf`
    auto stage = [&](int buf, int kt) {
#pragma unroll
        for (int half = 0; half < 2; half++) {
            int r0 = wv * 16 + half * 8;  // wave-uniform, multiple of 8
            async_ld16(&Kp[(size_t)(kt * 64 + r0 + rl) * 64 + sgo], &Ksb[buf][r0 * 64]);
            async_ld16(&Vp[(size_t)(r0 + rl) * 2048 + kt * 64 + sgo], &Vtb[buf][r0 * 64]);
        }
    };

    stage(0, k0);
    __syncthreads();  // drain prologue loads

    for (int kt = k0; kt < k1; kt++) {
        int cur = (kt - k0) & 1;
        if (kt + 1 < k1) stage(cur ^ 1, kt + 1);  // async; drained by end barrier
        const __bf16* Kc = Ksb[cur];
        const __bf16* Vc = Vtb[cur];
        // S^T: rows = 64 k (i*16+quad*4+r), cols = q (wv*32+qn*16+l16)
        f32x4 s[2][4] = {};
#pragma unroll
        for (int ks = 0; ks < 2; ks++) {
            bf16x8 kf[4];
#pragma unroll
            for (int i = 0; i < 4; i++)
                kf[i] = *(const bf16x8*)(
                    &Kc[(i * 16 + l16) * 64 + (((ks * 4 + quad) ^ swl) << 3)]);
#pragma unroll
            for (int i = 0; i < 4; i++)
#pragma unroll
                for (int qn = 0; qn < 2; qn++)
                    s[qn][i] = MFMA16(kf[i], qf[qn][ks], s[qn][i]);
        }
        // causal mask (elementwise only where the tile straddles the diagonal)
#pragma unroll
        for (int qn = 0; qn < 2; qn++) {
            int qmin = t * 128 + wv * 32 + qn * 16;
            if (kt * 64 + 63 > qmin) {
#pragma unroll
                for (int i = 0; i < 4; i++)
#pragma unroll
                    for (int r = 0; r < 4; r++)
                        if (kt * 64 + i * 16 + quad * 4 + r > qmin + l16) s[qn][i][r] = -1e30f;
            }
        }
        // exp2 (no max subtraction) + per-thread l accumulation + P write
#pragma unroll
        for (int qn = 0; qn < 2; qn++)
#pragma unroll
            for (int i = 0; i < 4; i++) {
                bf16x4 pk;
#pragma unroll
                for (int r = 0; r < 4; r++) {
                    float p = exp2f(s[qn][i][r]);
                    l_th[qn] += p;
                    pk[r] = (__bf16)p;
                }
                *(bf16x4*)(&Ps[(wv * 32 + qn * 16 + l16) * 72 + i * 16 + quad * 4]) = pk;
            }
        // O^T += V^T P^T (P is wave-private band; lgkmcnt orders write->read)
#pragma unroll
        for (int ks = 0; ks < 2; ks++) {
            bf16x8 pf[2];
#pragma unroll
            for (int qn = 0; qn < 2; qn++)
                pf[qn] = *(const bf16x8*)(
                    &Ps[(wv * 32 + qn * 16 + l16) * 72 + ks * 32 + quad * 8]);
            bf16x8 vf[4];
#pragma unroll
            for (int i = 0; i < 4; i++)
                vf[i] = *(const bf16x8*)(
                    &Vc[(i * 16 + l16) * 64 + (((ks * 4 + quad) ^ swl) << 3)]);
#pragma unroll
            for (int i = 0; i < 4; i++)
#pragma unroll
                for (int qn = 0; qn < 2; qn++)
                    acc_o[qn][i] = MFMA16(vf[i], pf[qn], acc_o[qn][i]);
        }
        __syncthreads();  // drains next-tile DMA; all reads of cur already done
    }
    // epilogue: partial (unnormalized O, l) for this chunk
    size_t pbase = (size_t)slot * 32 + bh;
#pragma unroll
    for (int qn = 0; qn < 2; qn++) {
        float ls = l_th[qn];
        ls += __shfl_xor(ls, 16);
        ls += __shfl_xor(ls, 32);
        int ql = wv * 32 + qn * 16 + l16;
        if (quad == 0) Lp[pbase * 128 + ql] = ls;
#pragma unroll
        for (int i = 0; i < 4; i++) {
            bf16x4 o4;
#pragma unroll
            for (int r = 0; r < 4; r++) o4[r] = (__bf16)acc_o[qn][i][r];
            *(bf16x4*)(&Op[(pbase * 128 + ql) * 64 + i * 16 + quad * 4]) = o4;
        }
    }
}

// Merge <=2 chunk partials per q-row, normalize, write AOb [B,S,E] bf16.
__global__ __launch_bounds__(256) void k_attn_combine(
    const __bf16* __restrict__ Op, const float* __restrict__ Lp,
    __bf16* __restrict__ AOb) {
    int gid = blockIdx.x * 256 + threadIdx.x;  // 32*2048*16 threads
    int d4 = gid & 15;
    int q = (gid >> 4) & 2047;
    int bh = gid >> 15;
    int t = q >> 7, ql = q & 127;
    int n = (t <= 7) ? 1 : 2;
    int base = (t <= 7) ? t : 8 + 2 * (t - 8);
    float L = 0.f, o[4] = {};
    for (int c = 0; c < n; c++) {
        size_t idx = (size_t)(base + c) * 32 + bh;
        L += Lp[idx * 128 + ql];
        bf16x4 p4 = *(const bf16x4*)(&Op[(idx * 128 + ql) * 64 + d4 * 4]);
#pragma unroll
        for (int r = 0; r < 4; r++) o[r] += (float)p4[r];
    }
    float inv = 1.f / L;
    int b = bh >> 4, h = bh & 15;
    bf16x4 o4;
#pragma unroll
    for (int r = 0; r < 4; r++) o4[r] = (__bf16)(o[r] * inv);
    *(bf16x4*)(&AOb[((size_t)b * 2048 + q) * 1024 + h * 64 + d4 * 4]) = o4;
}

// ---------------------------------------------------------------- launch
extern "C" void kernel_launch(void* const* d_in, const int* in_sizes, int n_in,
                              void* d_out, int out_size, void* d_ws, size_t ws_size,
                              hipStream_t stream) {
    const float* hs = (const float*)d_in[0];
    const float* w1 = (const float*)d_in[1];
    const float* b1 = (const float*)d_in[2];
    const float* w2 = (const float*)d_in[3];
    const float* b2 = (const float*)d_in[4];
    float* out = (float*)d_out;

    char* ws = (char*)d_ws;
    __bf16* hsb = (__bf16*)(ws);                               // [0,8M), dead after qkv
    __bf16* w1t = (__bf16*)(ws + (size_t)8 * 1024 * 1024);     // [8,14M), dead after qkv
    __bf16* w2t = (__bf16*)(ws + (size_t)14 * 1024 * 1024);    // [14,16M)
    __bf16* Qb  = (__bf16*)(ws + (size_t)16 * 1024 * 1024);    // [16,24M) [B,H,S,D]
    __bf16* Kb  = (__bf16*)(ws + (size_t)24 * 1024 * 1024);    // [24,32M) [B,H,S,D]
    __bf16* Vb  = (__bf16*)(ws + (size_t)32 * 1024 * 1024);    // [32,40M) [B,H,D,S]
    __bf16* AOb = (__bf16*)(ws + (size_t)40 * 1024 * 1024);    // [40,48M) [B,S,E]
    __bf16* Opart = (__bf16*)(ws);                             // [0,12.6M) overlays hsb/w1t
    float*  Lpart = (float*)(ws + (size_t)13 * 1024 * 1024);   // [13,13.4M)

    k_prep<<<8192, 256, 0, stream>>>(hs, w1, w2, hsb, w1t, w2t);
    k_gemm_qkv<<<dim3(24, 32), 256, 0, stream>>>(hsb, w1t, b1, Qb, Kb, Vb);
    k_attn<<<768, 256, 0, stream>>>(Qb, Kb, Vb, Opart, Lpart);
    k_attn_combine<<<4096, 256, 0, stream>>>(Opart, Lpart, AOb);
    k_gemm_proj<<<dim3(8, 64), 256, 0, stream>>>(AOb, w2t, b2, out);
}